// Round 1
// baseline (404.468 us; speedup 1.0000x reference)
//
#include <hip/hip_runtime.h>
#include <math.h>

#define BB 16
#define CC 512
#define HWN 4096
#define INNER 256
#define EPSV 1e-5f
#define CPB 64   // channels per block in streaming passes

// ---------------- block reduction helpers (256 threads = 4 waves) -------------
__device__ __forceinline__ float block_sum(float v, volatile float* s_red) {
    for (int off = 32; off; off >>= 1) v += __shfl_down(v, off);
    __syncthreads();
    if ((threadIdx.x & 63) == 0) s_red[threadIdx.x >> 6] = v;
    __syncthreads();
    return s_red[0] + s_red[1] + s_red[2] + s_red[3];
}
__device__ __forceinline__ float block_max(float v, volatile float* s_red) {
    for (int off = 32; off; off >>= 1) v = fmaxf(v, __shfl_down(v, off));
    __syncthreads();
    if ((threadIdx.x & 63) == 0) s_red[threadIdx.x >> 6] = v;
    __syncthreads();
    return fmaxf(fmaxf(s_red[0], s_red[1]), fmaxf(s_red[2], s_red[3]));
}

// ---------------- pass 1: cm_logits[b,hw] = x . Wcq ; xsum[b,c] = sum_hw x ----
__global__ __launch_bounds__(256) void k1_pass(
    const float* __restrict__ x, const float* __restrict__ wcq,
    float* __restrict__ cm_logits, float* __restrict__ xsum)
{
    const int t  = threadIdx.x;
    const int hw = blockIdx.x * 1024 + 4 * t;
    const int c0 = blockIdx.y * CPB;
    const int b  = blockIdx.z;
    __shared__ float s_w[CPB];
    if (t < CPB) s_w[t] = wcq[c0 + t];
    __syncthreads();

    const float* xb = x + ((size_t)b * CC + c0) * HWN + hw;
    float4 cm = {0.f, 0.f, 0.f, 0.f};
    for (int cl = 0; cl < CPB; ++cl) {
        float4 v = *(const float4*)(xb + (size_t)cl * HWN);
        float w = s_w[cl];
        cm.x = fmaf(v.x, w, cm.x);
        cm.y = fmaf(v.y, w, cm.y);
        cm.z = fmaf(v.z, w, cm.z);
        cm.w = fmaf(v.w, w, cm.w);
        float s = (v.x + v.y) + (v.z + v.w);
        for (int off = 32; off; off >>= 1) s += __shfl_down(s, off);
        if ((t & 63) == 0) atomicAdd(&xsum[b * CC + c0 + cl], s);
    }
    float* cp = cm_logits + b * HWN + hw;
    atomicAdd(cp + 0, cm.x);
    atomicAdd(cp + 1, cm.y);
    atomicAdd(cp + 2, cm.z);
    atomicAdd(cp + 3, cm.w);
}

// ---------------- small per-batch kernel: softmaxes + wsv_eff -----------------
__global__ __launch_bounds__(256) void k2_small(
    const float* __restrict__ Wsq, const float* __restrict__ Wsv,
    const float* __restrict__ cm_logits, const float* __restrict__ xsum,
    float* __restrict__ cm_sm, float* __restrict__ wsv_eff)
{
    const int b = blockIdx.x;
    const int t = threadIdx.x;
    __shared__ float s_red[4];
    __shared__ float s_xsum[CC];
    __shared__ float s_avg[INNER];

    // (a) softmax over cm_logits[b,:]  -> cm_sm
    const float* cl = cm_logits + b * HWN;
    float* co = cm_sm + b * HWN;
    float lmax = -1e30f;
    for (int i = t; i < HWN; i += 256) lmax = fmaxf(lmax, cl[i]);
    lmax = block_max(lmax, s_red);
    float lsum = 0.f;
    for (int i = t; i < HWN; i += 256) {
        float e = __expf(cl[i] - lmax);
        co[i] = e;
        lsum += e;
    }
    lsum = block_sum(lsum, s_red);
    float rinv = 1.f / lsum;
    for (int i = t; i < HWN; i += 256) co[i] *= rinv;

    // load xsum[b,:] to LDS
    s_xsum[t]       = xsum[b * CC + t];
    s_xsum[t + 256] = xsum[b * CC + t + 256];
    __syncthreads();

    // (b) avg[k] = (Wsq @ xsum)/HW ; softmax over k (thread t == k)
    float acc = 0.f;
    const float* wr = Wsq + (size_t)t * CC;
    for (int c = 0; c < CC; ++c) acc = fmaf(wr[c], s_xsum[c], acc);
    float a = acc * (1.0f / HWN);
    float m2 = block_max(a, s_red);
    float e = __expf(a - m2);
    float s2 = block_sum(e, s_red);
    s_avg[t] = e / s2;
    __syncthreads();

    // (c) wsv_eff[b,c] = sum_k avg_sm[k] * Wsv[k,c]
    float a0 = 0.f, a1 = 0.f;
    for (int k = 0; k < INNER; ++k) {
        float av = s_avg[k];
        a0 = fmaf(av, Wsv[(size_t)k * CC + t], a0);
        a1 = fmaf(av, Wsv[(size_t)k * CC + t + 256], a1);
    }
    wsv_eff[b * CC + t]       = a0;
    wsv_eff[b * CC + t + 256] = a1;
}

// ---------------- pass 2: ctx[b,hw] = x . wsv_eff ; xw[b,c] = sum_hw x*cm_sm --
__global__ __launch_bounds__(256) void k3_pass(
    const float* __restrict__ x, const float* __restrict__ wsv_eff,
    const float* __restrict__ cm_sm, float* __restrict__ ctx, float* __restrict__ xw)
{
    const int t  = threadIdx.x;
    const int hw = blockIdx.x * 1024 + 4 * t;
    const int c0 = blockIdx.y * CPB;
    const int b  = blockIdx.z;
    __shared__ float s_w[CPB];
    if (t < CPB) s_w[t] = wsv_eff[b * CC + c0 + t];
    __syncthreads();

    float4 wm = *(const float4*)(cm_sm + b * HWN + hw);
    const float* xb = x + ((size_t)b * CC + c0) * HWN + hw;
    float4 acc = {0.f, 0.f, 0.f, 0.f};
    for (int cl = 0; cl < CPB; ++cl) {
        float4 v = *(const float4*)(xb + (size_t)cl * HWN);
        float w = s_w[cl];
        acc.x = fmaf(v.x, w, acc.x);
        acc.y = fmaf(v.y, w, acc.y);
        acc.z = fmaf(v.z, w, acc.z);
        acc.w = fmaf(v.w, w, acc.w);
        float s = fmaf(v.x, wm.x, fmaf(v.y, wm.y, fmaf(v.z, wm.z, v.w * wm.w)));
        for (int off = 32; off; off >>= 1) s += __shfl_down(s, off);
        if ((t & 63) == 0) atomicAdd(&xw[b * CC + c0 + cl], s);
    }
    float* cp = ctx + b * HWN + hw;
    atomicAdd(cp + 0, acc.x);
    atomicAdd(cp + 1, acc.y);
    atomicAdd(cp + 2, acc.z);
    atomicAdd(cp + 3, acc.w);
}

// ---------------- small per-batch kernel: context -> z -> LN -> mask ----------
__global__ __launch_bounds__(256) void k4_small(
    const float* __restrict__ Wcv, const float* __restrict__ Wcz,
    const float* __restrict__ gamma, const float* __restrict__ beta,
    const float* __restrict__ xw, float* __restrict__ mask)
{
    const int b = blockIdx.x, t = threadIdx.x;
    __shared__ float s_red[4];
    __shared__ float s_xw[CC];
    __shared__ float s_ctx[INNER];
    s_xw[t]       = xw[b * CC + t];
    s_xw[t + 256] = xw[b * CC + t + 256];
    __syncthreads();

    // context[k] = Wcv[k,:] . xw[b,:]
    float acc = 0.f;
    const float* wr = Wcv + (size_t)t * CC;
    for (int c = 0; c < CC; ++c) acc = fmaf(wr[c], s_xw[c], acc);
    s_ctx[t] = acc;
    __syncthreads();

    // z[o] = Wcz[o,:] . context  (o = t and t+256)
    float z0 = 0.f, z1 = 0.f;
    const float* r0 = Wcz + (size_t)t * INNER;
    const float* r1 = Wcz + (size_t)(t + 256) * INNER;
    for (int k = 0; k < INNER; ++k) {
        float cv = s_ctx[k];
        z0 = fmaf(r0[k], cv, z0);
        z1 = fmaf(r1[k], cv, z1);
    }
    // LayerNorm over 512
    float mu = block_sum(z0 + z1, s_red) * (1.f / CC);
    float d0 = z0 - mu, d1 = z1 - mu;
    float var = block_sum(d0 * d0 + d1 * d1, s_red) * (1.f / CC);
    float rstd = rsqrtf(var + EPSV);
    float zn0 = fmaf(d0 * rstd, gamma[t], beta[t]);
    float zn1 = fmaf(d1 * rstd, gamma[t + 256], beta[t + 256]);
    mask[b * CC + t]       = 1.f / (1.f + __expf(-zn0));
    mask[b * CC + t + 256] = 1.f / (1.f + __expf(-zn1));
}

// ---------------- final: out = x * (mask[b,c] + sigmoid(ctx[b,hw])) ----------
__global__ __launch_bounds__(256) void k5_final(
    const float* __restrict__ x, const float* __restrict__ ctx,
    const float* __restrict__ mask, float* __restrict__ out)
{
    const int t  = threadIdx.x;
    const int hw = blockIdx.x * 1024 + 4 * t;
    const int c  = blockIdx.y;
    const int b  = blockIdx.z;
    const float m = mask[b * CC + c];
    float4 cv = *(const float4*)(ctx + b * HWN + hw);
    float4 s;
    s.x = 1.f / (1.f + __expf(-cv.x));
    s.y = 1.f / (1.f + __expf(-cv.y));
    s.z = 1.f / (1.f + __expf(-cv.z));
    s.w = 1.f / (1.f + __expf(-cv.w));
    const size_t base = ((size_t)b * CC + c) * HWN + hw;
    float4 xv = *(const float4*)(x + base);
    float4 o;
    o.x = xv.x * (m + s.x);
    o.y = xv.y * (m + s.y);
    o.z = xv.z * (m + s.z);
    o.w = xv.w * (m + s.w);
    *(float4*)(out + base) = o;
}

extern "C" void kernel_launch(void* const* d_in, const int* in_sizes, int n_in,
                              void* d_out, int out_size, void* d_ws, size_t ws_size,
                              hipStream_t stream) {
    const float* x     = (const float*)d_in[0];
    const float* Wsq   = (const float*)d_in[1];
    const float* Wsv   = (const float*)d_in[2];
    const float* Wcq   = (const float*)d_in[3];
    const float* Wcv   = (const float*)d_in[4];
    const float* Wcz   = (const float*)d_in[5];
    const float* gamma = (const float*)d_in[6];
    const float* beta  = (const float*)d_in[7];
    float* out = (float*)d_out;
    float* ws  = (float*)d_ws;

    // ws layout (floats):
    float* cm_logits = ws;             // 65536  (atomic-accumulated -> zeroed)
    float* ctx       = ws + 65536;     // 65536  (atomic-accumulated -> zeroed)
    float* xsum      = ws + 131072;    // 8192   (atomic-accumulated -> zeroed)
    float* xw        = ws + 139264;    // 8192   (atomic-accumulated -> zeroed)
    float* cm_sm     = ws + 147456;    // 65536
    float* wsv_eff   = ws + 212992;    // 8192
    float* mask      = ws + 221184;    // 8192
    // total: 229376 floats = 896 KiB

    hipMemsetAsync(d_ws, 0, 147456 * sizeof(float), stream);

    k1_pass<<<dim3(4, 8, BB), 256, 0, stream>>>(x, Wcq, cm_logits, xsum);
    k2_small<<<BB, 256, 0, stream>>>(Wsq, Wsv, cm_logits, xsum, cm_sm, wsv_eff);
    k3_pass<<<dim3(4, 8, BB), 256, 0, stream>>>(x, wsv_eff, cm_sm, ctx, xw);
    k4_small<<<BB, 256, 0, stream>>>(Wcv, Wcz, gamma, beta, xw, mask);
    k5_final<<<dim3(4, CC, BB), 256, 0, stream>>>(x, ctx, mask, out);
}